// Round 7
// baseline (252.566 us; speedup 1.0000x reference)
//
#include <hip/hip_runtime.h>

#define CC 8
#define HH 256
#define WW 512
#define KK 9
#define XF 272   // LDS floats per (wave,buf): 264 used, padded to 16B multiple

// ILP build: barrier-free + filter-stream register double-buffer.
// R1 proved prefetch is nullified by the pre-barrier vmcnt(0) drain; R2-R6
// proved the kernel is latency-bound and that per-wave in-flight load depth
// (not TLP, not schedule) is the binding constraint (R4/R6: VGPR 40 ->
// serialized loads -> 79/51us; R5: spill -> 115us). This kernel combines the
// two: no barriers anywhere AND fb[9] float4 prefetch held live across the
// FMA block, forcing ~9 loads in flight. All memory waits (ds_write of staged
// x, fa<-fb rotate) land AFTER the FMAs. 1 ch/wave keeps VGPR ~110 <= 128
// (launch_bounds(256,4): no forced squeeze -> no spill, no <=40 starvation).
__global__ __launch_bounds__(256, 4) void dynfilter_kernel(
    const float* __restrict__ x,
    const float* __restrict__ filt,
    const float* __restrict__ fbias,
    float* __restrict__ out)
{
    __shared__ __align__(16) float xs[4][2][XF];   // 8704 B/block

    const int tid  = threadIdx.x;
    const int wv   = tid >> 6;          // wave -> channel cgrp*4 + wv
    const int lane = tid & 63;

    // XCD-aware bijective swizzle: nwg=2048 -> 256 contiguous work items/XCD.
    const int bid0 = blockIdx.x;
    const int bid  = ((bid0 & 7) << 8) | (bid0 >> 3);

    const int cgrp = bid & 1;
    const int seg  = (bid >> 1) & 1;
    const int h    = (bid >> 2) & 255;
    const int n    = bid >> 10;

    const int w0      = seg * 256 + (lane << 2);   // 4 px per lane
    const int wstage0 = seg * 256 - 4;

    const size_t HW = (size_t)HH * WW;
    const int c = (cgrp << 2) + wv;

    const float* xrow = x + (size_t)(n * CC + c) * HW + wstage0;
    const float* fptr = filt + ((size_t)(n * 81) * HH + h) * WW + w0;

    float acc[4];
    {
        const float4 b4 = *(const float4*)(fbias + ((size_t)(n * HH + h)) * WW + w0);
        acc[0] = b4.x; acc[1] = b4.y; acc[2] = b4.z; acc[3] = b4.w;
    }

    // staging chunk validity (window = 264 floats: main 256 + tail 8)
    const bool main_ok = (unsigned)(wstage0 + (lane << 2)) < (unsigned)WW;
    const bool tail_ok = (lane < 2) && ((unsigned)(wstage0 + 256 + (lane << 2)) < (unsigned)WW);

    // ---- prologue: stage row h-4 into buf 0; prefetch tap-row 0 into fa ----
    {
        const int hh = h - 4;
        const bool rowok = hh >= 0;
        const float* src = xrow + (size_t)hh * WW;
        float4 sm = make_float4(0.f, 0.f, 0.f, 0.f), st = sm;
        if (rowok && main_ok) sm = *(const float4*)(src + (lane << 2));
        if (rowok && tail_ok) st = *(const float4*)(src + 256 + (lane << 2));
        *(float4*)&xs[wv][0][lane << 2] = sm;
        if (lane < 2) *(float4*)&xs[wv][0][256 + (lane << 2)] = st;
    }

    float4 fa[9];
    #pragma unroll
    for (int j = 0; j < 9; ++j) fa[j] = *(const float4*)(fptr + (size_t)j * HW);

    // CRITICAL: compiler auto-unrolls trip-count-9 loops, then hoists all 81
    // filter loads -> VGPR blowup + spill. unroll(disable) is the fix.
    #pragma clang loop unroll(disable)
    for (int i = 0; i < KK; ++i) {
        const int buf = i & 1;

        // 1) issue next-row x staging loads (consumed at step 5, post-FMA)
        float4 sm = make_float4(0.f, 0.f, 0.f, 0.f), st = sm;
        if (i < KK - 1) {
            const int hh = h - 3 + i;
            const bool rowok = (unsigned)hh < (unsigned)HH;
            const float* src = xrow + (size_t)hh * WW;
            if (rowok && main_ok) sm = *(const float4*)(src + (lane << 2));
            if (rowok && tail_ok) st = *(const float4*)(src + 256 + (lane << 2));
        }

        // 2) issue NEXT tap-row's 9 filter loads (consumed next iter; the
        //    wait for these lands at step 6, after the FMA block)
        float4 fb[9];
        if (i < KK - 1) {
            const float* fi = fptr + (size_t)(i + 1) * KK * HW;
            #pragma unroll
            for (int j = 0; j < 9; ++j) fb[j] = *(const float4*)(fi + (size_t)j * HW);
        }

        // 3) x window from wave-private LDS: 12 floats (rel start = 4*lane)
        float v[12];
        {
            const float* p = &xs[wv][buf][lane << 2];
            float4 u;
            u = *(const float4*)(p + 0); v[0]=u.x; v[1]=u.y; v[2] =u.z; v[3] =u.w;
            u = *(const float4*)(p + 4); v[4]=u.x; v[5]=u.y; v[6] =u.z; v[7] =u.w;
            u = *(const float4*)(p + 8); v[8]=u.x; v[9]=u.y; v[10]=u.z; v[11]=u.w;
        }

        // 4) 36 FMAs with CURRENT taps (fa loaded last iter: no vmem wait)
        #pragma unroll
        for (int j = 0; j < 9; ++j) {
            acc[0] = fmaf(fa[j].x, v[j+0], acc[0]);
            acc[1] = fmaf(fa[j].y, v[j+1], acc[1]);
            acc[2] = fmaf(fa[j].z, v[j+2], acc[2]);
            acc[3] = fmaf(fa[j].w, v[j+3], acc[3]);
        }

        // 5) store staged row into the other wave-private buffer
        if (i < KK - 1) {
            *(float4*)&xs[wv][buf ^ 1][lane << 2] = sm;
            if (lane < 2) *(float4*)&xs[wv][buf ^ 1][256 + (lane << 2)] = st;
        }

        // 6) rotate filter double-buffer (vmcnt wait for fb lands here)
        if (i < KK - 1) {
            #pragma unroll
            for (int j = 0; j < 9; ++j) fa[j] = fb[j];
        }
    }

    *(float4*)(out + ((size_t)(n * CC + c) * HH + h) * WW + w0) =
        make_float4(acc[0], acc[1], acc[2], acc[3]);
}

extern "C" void kernel_launch(void* const* d_in, const int* in_sizes, int n_in,
                              void* d_out, int out_size, void* d_ws, size_t ws_size,
                              hipStream_t stream) {
    const float* x  = (const float*)d_in[0];
    const float* f  = (const float*)d_in[1];
    const float* fb = (const float*)d_in[2];
    float* o = (float*)d_out;
    hipLaunchKernelGGL(dynfilter_kernel, dim3(2048), dim3(256), 0, stream,
                       x, f, fb, o);
}

// Round 9
// 140.955 us; speedup vs baseline: 1.7918x; 1.7918x over previous
//
#include <hip/hip_runtime.h>

#define CC 8
#define HH 256
#define WW 512
#define KK 9
#define HWU (HH * WW)   // 131072 floats per channel image
#define XF 272          // x window row: 264 used, padded to 16B multiple

// global_load_lds pipeline, v2 (R8 post-mortem fixes):
//  - per-iteration RAW s_barrier (no vmcnt drain) bounds wave drift -> the
//    block-shared flds double-buffer is race-free (R8 bug #1)
//  - all gll ops run FULL-EXEC with clamped addresses; known-invalid cells
//    (halo w<0 / w>=512, rows outside [0,256)) are zeroed by ds_write after
//    the vmcnt wait -> no reliance on masked-lane gll semantics (R8 bug #2)
//  - steady-state s_waitcnt vmcnt(13): x(i+1)[4] + f(i+1)[9] stay in flight;
//    never drains to 0 inside the loop (T3/T4)
__device__ __forceinline__ void gll16(const float* g, float* l) {
    __builtin_amdgcn_global_load_lds(
        (const __attribute__((address_space(1))) float*)g,
        (__attribute__((address_space(3))) float*)l,
        16, 0, 0);
}

__global__ __launch_bounds__(256, 4) void dynfilter_kernel(
    const float* __restrict__ x,
    const float* __restrict__ filt,
    const float* __restrict__ fbias,
    float* __restrict__ out)
{
    __shared__ __align__(16) float flds[2][KK][256];   // 18432 B, block-shared taps
    __shared__ __align__(16) float xs[4][2][2][XF];    // 17408 B, wave-private x rows

    const int tid  = threadIdx.x;
    const int wv   = tid >> 6;          // wave -> channels {2wv, 2wv+1}
    const int lane = tid & 63;

    // XCD-aware bijective swizzle (nwg=1024 % 8 == 0)
    const int bid0 = blockIdx.x;
    const int bid  = ((bid0 & 7) << 7) | (bid0 >> 3);

    const int seg = bid & 1;
    const int h   = (bid >> 1) & 255;
    const int n   = bid >> 9;

    const int w0      = seg * 256 + (lane << 2);   // 4 px per lane
    const int wstage0 = seg * 256 - 4;

    const int c0 = wv << 1;

    const float* fblk = filt + (size_t)(n * 81 * HH + h) * WW + seg * 256;
    const float* x0   = x + (size_t)(n * CC + c0) * HWU;
    const float* x1   = x0 + HWU;

    // full-exec per-lane window sources, clamped into [0, WW-4]:
    //   load A covers window[0..255]  (w = wstage0     + 4*lane)
    //   load B covers window[8..263]  (w = wstage0 + 8 + 4*lane)
    // overlap [8..255] is double-written with identical bytes (benign).
    // clamping fires only at: seg0 loadA lane0 (w=-4) and seg1 loadB lane63
    // (w=512) -> exactly the halo cells fix_x re-zeroes.
    int wA = wstage0 + (lane << 2);
    int wB = wstage0 + 8 + (lane << 2);
    wA = wA < 0 ? 0 : (wA > WW - 4 ? WW - 4 : wA);
    wB = wB < 0 ? 0 : (wB > WW - 4 ? WW - 4 : wB);

    float acc0[4] = {0.f, 0.f, 0.f, 0.f};
    float acc1[4] = {0.f, 0.f, 0.f, 0.f};

    // issue one x row into wave-private buffer xb: exactly 4 vmcnt ops
    auto stage_x = [&](int r, int xb) {
        int hh = h - 4 + r;
        hh = hh < 0 ? 0 : (hh > HH - 1 ? HH - 1 : hh);
        const size_t ro = (size_t)hh * WW;
        float* d0 = &xs[wv][xb][0][0];
        float* d1 = &xs[wv][xb][1][0];
        gll16(x0 + ro + wA, d0);
        gll16(x0 + ro + wB, d0 + 8);
        gll16(x1 + ro + wA, d1);
        gll16(x1 + ro + wB, d1 + 8);
    };

    // issue one filter tap-row (9 taps): exactly 9 vmcnt ops (all waves stage
    // identical data to identical addresses -> idempotent; each wave's own
    // vmcnt wait guarantees ITS copy landed, so values are always correct)
    auto stage_f = [&](const float* frow, int fb) {
        float* d = &flds[fb][0][0];
        #pragma unroll
        for (int j = 0; j < KK; ++j)
            gll16(frow + (size_t)j * HWU + (lane << 2), d + j * 256);
    };

    // post-vmcnt cleanup of buffer xb holding row (h-4+r), before ds_reads:
    // whole-row zero if the row is outside the image, else zero the 4 halo
    // floats (seg0: window[0..3] = w<0; seg1: window[260..263] = w>=512)
    auto fix_x = [&](int xb, int r) {
        const float4 z = make_float4(0.f, 0.f, 0.f, 0.f);
        const int hh = h - 4 + r;
        if ((unsigned)hh >= (unsigned)HH) {
            *(float4*)&xs[wv][xb][0][lane << 2] = z;
            *(float4*)&xs[wv][xb][1][lane << 2] = z;
            if (lane < 2) {
                *(float4*)&xs[wv][xb][0][256 + (lane << 2)] = z;
                *(float4*)&xs[wv][xb][1][256 + (lane << 2)] = z;
            }
        } else if (lane < 2) {
            *(float4*)&xs[wv][xb][lane][seg ? 260 : 0] = z;
        }
    };

    // drain any compiler-issued VMEM so manual vmcnt counting is exact
    asm volatile("s_waitcnt vmcnt(0)" ::: "memory");

    // ---- prologue: f(0)[9], x(0)[4], x(1)[4] in flight ----
    stage_f(fblk, 0);
    stage_x(0, 0);
    stage_x(1, 1);

    const float* frow = fblk + 9 * HWU;   // tap-row 1

    #pragma clang loop unroll(disable)
    for (int i = 0; i < KK - 1; ++i) {
        const int buf = i & 1;

        stage_f(frow, buf ^ 1);           // f(i+1): 9 ops
        frow += 9 * HWU;

        // newest in flight: x(i+1)[4] + f(i+1)[9] = 13 -> f(i), x(i) landed
        asm volatile("s_waitcnt vmcnt(13)" ::: "memory");
        __builtin_amdgcn_sched_barrier(0);

        fix_x(buf, i);
        __builtin_amdgcn_sched_barrier(0);

        // reads (same-wave LDS pipe is in-order: sees fix_x's zeros)
        float4 f[9];
        {
            const float* fp = &flds[buf][0][lane << 2];
            #pragma unroll
            for (int j = 0; j < 9; ++j) f[j] = *(const float4*)(fp + j * 256);
        }
        float v0[12], v1[12];
        {
            const float* p0 = &xs[wv][buf][0][lane << 2];
            const float* p1 = &xs[wv][buf][1][lane << 2];
            float4 u;
            u = *(const float4*)(p0 + 0); v0[0]=u.x; v0[1]=u.y; v0[2] =u.z; v0[3] =u.w;
            u = *(const float4*)(p0 + 4); v0[4]=u.x; v0[5]=u.y; v0[6] =u.z; v0[7] =u.w;
            u = *(const float4*)(p0 + 8); v0[8]=u.x; v0[9]=u.y; v0[10]=u.z; v0[11]=u.w;
            u = *(const float4*)(p1 + 0); v1[0]=u.x; v1[1]=u.y; v1[2] =u.z; v1[3] =u.w;
            u = *(const float4*)(p1 + 4); v1[4]=u.x; v1[5]=u.y; v1[6] =u.z; v1[7] =u.w;
            u = *(const float4*)(p1 + 8); v1[8]=u.x; v1[9]=u.y; v1[10]=u.z; v1[11]=u.w;
        }

        // 72 FMAs (2 ch x 4 px x 9 taps)
        #pragma unroll
        for (int j = 0; j < 9; ++j) {
            acc0[0] = fmaf(f[j].x, v0[j+0], acc0[0]);
            acc0[1] = fmaf(f[j].y, v0[j+1], acc0[1]);
            acc0[2] = fmaf(f[j].z, v0[j+2], acc0[2]);
            acc0[3] = fmaf(f[j].w, v0[j+3], acc0[3]);
            acc1[0] = fmaf(f[j].x, v1[j+0], acc1[0]);
            acc1[1] = fmaf(f[j].y, v1[j+1], acc1[1]);
            acc1[2] = fmaf(f[j].z, v1[j+2], acc1[2]);
            acc1[3] = fmaf(f[j].w, v1[j+3], acc1[3]);
        }

        // refill the just-consumed buffer with row i+2. Pinned after the FMA
        // block: the ds_reads above are provably retired (their data fed the
        // FMAs via lgkmcnt), so the incoming LDS writes cannot race them.
        __builtin_amdgcn_sched_barrier(0);
        stage_x(i + 2, buf);              // x(i+2): 4 ops

        // RAW barrier (no vmcnt drain): bounds wave drift to 0 iterations so
        // next iteration's stage_f into flds[buf] can't race lagging readers.
        __builtin_amdgcn_sched_barrier(0);
        __builtin_amdgcn_s_barrier();
        __builtin_amdgcn_sched_barrier(0);
    }

    // ---- epilogue (row h+4, buffer 0, taps f(8) in flds[0]) ----
    // newest in flight: x(9)[4] -> f(8), x(8) landed
    asm volatile("s_waitcnt vmcnt(4)" ::: "memory");
    __builtin_amdgcn_sched_barrier(0);

    fix_x(0, 8);
    __builtin_amdgcn_sched_barrier(0);

    {
        float4 f[9];
        const float* fp = &flds[0][0][lane << 2];
        #pragma unroll
        for (int j = 0; j < 9; ++j) f[j] = *(const float4*)(fp + j * 256);

        float v0[12], v1[12];
        const float* p0 = &xs[wv][0][0][lane << 2];
        const float* p1 = &xs[wv][0][1][lane << 2];
        float4 u;
        u = *(const float4*)(p0 + 0); v0[0]=u.x; v0[1]=u.y; v0[2] =u.z; v0[3] =u.w;
        u = *(const float4*)(p0 + 4); v0[4]=u.x; v0[5]=u.y; v0[6] =u.z; v0[7] =u.w;
        u = *(const float4*)(p0 + 8); v0[8]=u.x; v0[9]=u.y; v0[10]=u.z; v0[11]=u.w;
        u = *(const float4*)(p1 + 0); v1[0]=u.x; v1[1]=u.y; v1[2] =u.z; v1[3] =u.w;
        u = *(const float4*)(p1 + 4); v1[4]=u.x; v1[5]=u.y; v1[6] =u.z; v1[7] =u.w;
        u = *(const float4*)(p1 + 8); v1[8]=u.x; v1[9]=u.y; v1[10]=u.z; v1[11]=u.w;

        #pragma unroll
        for (int j = 0; j < 9; ++j) {
            acc0[0] = fmaf(f[j].x, v0[j+0], acc0[0]);
            acc0[1] = fmaf(f[j].y, v0[j+1], acc0[1]);
            acc0[2] = fmaf(f[j].z, v0[j+2], acc0[2]);
            acc0[3] = fmaf(f[j].w, v0[j+3], acc0[3]);
            acc1[0] = fmaf(f[j].x, v1[j+0], acc1[0]);
            acc1[1] = fmaf(f[j].y, v1[j+1], acc1[1]);
            acc1[2] = fmaf(f[j].z, v1[j+2], acc1[2]);
            acc1[3] = fmaf(f[j].w, v1[j+3], acc1[3]);
        }
    }

    // bias (loaded only now, after the last counted wait) + store
    {
        const float4 b4 = *(const float4*)(fbias + ((size_t)(n * HH + h)) * WW + w0);
        const float4 o0 = make_float4(acc0[0] + b4.x, acc0[1] + b4.y,
                                      acc0[2] + b4.z, acc0[3] + b4.w);
        const float4 o1 = make_float4(acc1[0] + b4.x, acc1[1] + b4.y,
                                      acc1[2] + b4.z, acc1[3] + b4.w);
        *(float4*)(out + ((size_t)(n * CC + c0)     * HH + h) * WW + w0) = o0;
        *(float4*)(out + ((size_t)(n * CC + c0 + 1) * HH + h) * WW + w0) = o1;
    }
}

extern "C" void kernel_launch(void* const* d_in, const int* in_sizes, int n_in,
                              void* d_out, int out_size, void* d_ws, size_t ws_size,
                              hipStream_t stream) {
    const float* x  = (const float*)d_in[0];
    const float* f  = (const float*)d_in[1];
    const float* fb = (const float*)d_in[2];
    float* o = (float*)d_out;
    hipLaunchKernelGGL(dynfilter_kernel, dim3(1024), dim3(256), 0, stream,
                       x, f, fb, o);
}

// Round 10
// 136.263 us; speedup vs baseline: 1.8535x; 1.0344x over previous
//
#include <hip/hip_runtime.h>

#define CC 8
#define HH 256
#define WW 512
#define KK 9
#define XF 272   // LDS floats per (wave,buf,ch) row: 264 used, padded to 16B multiple

// FINAL (reverted to the session-best R3 variant, 136.99 us measured).
// Session evidence (10 structural variants): the ~35-40 us kernel plateau is
// invariant to schedule (R0-R3), TLP (R5/R6), register ILP (R1/R7), and a
// counted-vmcnt global_load_lds pipeline with 13 loads in flight (R9).
// Remaining gap to the ~17 us traffic floor is attributed to harness-side
// fill/writeback contention (the timed graph is 75% poison-fill at 83% of
// HBM peak). Keep: wave-private LDS double-buffer, zero barriers, XCD-aware
// bijective swizzle, unroll(disable) on the tap-row loop.
__global__ __launch_bounds__(256, 4) void dynfilter_kernel(
    const float* __restrict__ x,
    const float* __restrict__ filt,
    const float* __restrict__ fbias,
    float* __restrict__ out)
{
    // Wave-private LDS double buffer: NO __syncthreads in this kernel.
    __shared__ __align__(16) float xs[4][2][2][XF];

    const int tid  = threadIdx.x;
    const int wv   = tid >> 6;          // wave -> channels {2wv, 2wv+1}
    const int lane = tid & 63;

    // XCD-aware bijective swizzle (nwg=1024, 8 XCDs, 128 blocks each).
    const int bid0 = blockIdx.x;
    const int bid  = ((bid0 & 7) << 7) | (bid0 >> 3);   // (bid0%8)*128 + bid0/8

    const int seg = bid & 1;
    const int h   = (bid >> 1) & 255;
    const int n   = bid >> 9;

    const int w0      = seg * 256 + (lane << 2);  // 4 px per lane
    const int wstage0 = seg * 256 - 4;

    const size_t HW = (size_t)HH * WW;
    const int c0 = wv << 1;

    const float* xr0  = x + (size_t)(n * CC + c0)     * HW + wstage0;
    const float* xr1  = x + (size_t)(n * CC + c0 + 1) * HW + wstage0;
    const float* fptr = filt + ((size_t)(n * 81) * HH + h) * WW + w0;

    float acc0[4], acc1[4];
    {
        const float4 b4 = *(const float4*)(fbias + ((size_t)(n * HH + h)) * WW + w0);
        acc0[0]=b4.x; acc0[1]=b4.y; acc0[2]=b4.z; acc0[3]=b4.w;
        acc1[0]=b4.x; acc1[1]=b4.y; acc1[2]=b4.z; acc1[3]=b4.w;
    }

    const int wlo = wstage0 + (lane << 2);         // main float4 start coord
    const int whi = wstage0 + 256 + (lane << 2);   // tail float4 (lanes 0,1)
    const bool lo_ok = (unsigned)wlo < (unsigned)WW;
    const bool hi_ok = (lane < 2) && ((unsigned)whi < (unsigned)WW);

    // ---- prologue: stage row h-4 into buf 0 (wave-private, no barrier) ----
    {
        const int hh = h - 4;
        const bool rowok = hh >= 0;
        const float* s0 = xr0 + (size_t)hh * WW;
        const float* s1 = xr1 + (size_t)hh * WW;
        float4 a0 = make_float4(0.f,0.f,0.f,0.f), b0 = a0, a1 = a0, b1 = a0;
        if (rowok && lo_ok) { a0 = *(const float4*)(s0 + (lane<<2));       a1 = *(const float4*)(s1 + (lane<<2)); }
        if (rowok && hi_ok) { b0 = *(const float4*)(s0 + 256 + (lane<<2)); b1 = *(const float4*)(s1 + 256 + (lane<<2)); }
        *(float4*)&xs[wv][0][0][lane<<2] = a0;
        *(float4*)&xs[wv][0][1][lane<<2] = a1;
        if (lane < 2) {
            *(float4*)&xs[wv][0][0][256 + (lane<<2)] = b0;
            *(float4*)&xs[wv][0][1][256 + (lane<<2)] = b1;
        }
    }

    // CRITICAL: compiler auto-unrolls trip-count-9 loops, then hoists all 81
    // filter loads -> 256 VGPR + scratch spill. unroll(disable) is the fix.
    #pragma clang loop unroll(disable)
    for (int i = 0; i < KK; ++i) {
        const int buf = i & 1;

        // 1) issue next-row x staging loads first (consumed last this iter)
        float4 a0 = make_float4(0.f,0.f,0.f,0.f), b0 = a0, a1 = a0, b1 = a0;
        if (i < KK - 1) {
            const int hh = h - 3 + i;
            const bool rowok = (unsigned)hh < (unsigned)HH;
            const float* s0 = xr0 + (size_t)hh * WW;
            const float* s1 = xr1 + (size_t)hh * WW;
            if (rowok && lo_ok) { a0 = *(const float4*)(s0 + (lane<<2));       a1 = *(const float4*)(s1 + (lane<<2)); }
            if (rowok && hi_ok) { b0 = *(const float4*)(s0 + 256 + (lane<<2)); b1 = *(const float4*)(s1 + 256 + (lane<<2)); }
        }

        // 2) filter taps for row i: 9 coalesced float4 loads (4 px per lane)
        float4 f[9];
        {
            const float* fi = fptr + (size_t)i * KK * HW;
            #pragma unroll
            for (int j = 0; j < 9; ++j) f[j] = *(const float4*)(fi + (size_t)j * HW);
        }

        // 3) x window from wave-private LDS: 12 floats per channel
        float v0[12], v1[12];
        {
            const float* p0 = &xs[wv][buf][0][lane << 2];
            const float* p1 = &xs[wv][buf][1][lane << 2];
            float4 u;
            u = *(const float4*)(p0 + 0); v0[0]=u.x; v0[1]=u.y; v0[2] =u.z; v0[3] =u.w;
            u = *(const float4*)(p0 + 4); v0[4]=u.x; v0[5]=u.y; v0[6] =u.z; v0[7] =u.w;
            u = *(const float4*)(p0 + 8); v0[8]=u.x; v0[9]=u.y; v0[10]=u.z; v0[11]=u.w;
            u = *(const float4*)(p1 + 0); v1[0]=u.x; v1[1]=u.y; v1[2] =u.z; v1[3] =u.w;
            u = *(const float4*)(p1 + 4); v1[4]=u.x; v1[5]=u.y; v1[6] =u.z; v1[7] =u.w;
            u = *(const float4*)(p1 + 8); v1[8]=u.x; v1[9]=u.y; v1[10]=u.z; v1[11]=u.w;
        }

        // 4) 72 FMAs (2 ch x 4 px x 9 taps)
        #pragma unroll
        for (int j = 0; j < 9; ++j) {
            acc0[0] = fmaf(f[j].x, v0[j+0], acc0[0]);
            acc0[1] = fmaf(f[j].y, v0[j+1], acc0[1]);
            acc0[2] = fmaf(f[j].z, v0[j+2], acc0[2]);
            acc0[3] = fmaf(f[j].w, v0[j+3], acc0[3]);
            acc1[0] = fmaf(f[j].x, v1[j+0], acc1[0]);
            acc1[1] = fmaf(f[j].y, v1[j+1], acc1[1]);
            acc1[2] = fmaf(f[j].z, v1[j+2], acc1[2]);
            acc1[3] = fmaf(f[j].w, v1[j+3], acc1[3]);
        }

        // 5) store staged row into the other wave-private buffer
        if (i < KK - 1) {
            *(float4*)&xs[wv][buf ^ 1][0][lane<<2] = a0;
            *(float4*)&xs[wv][buf ^ 1][1][lane<<2] = a1;
            if (lane < 2) {
                *(float4*)&xs[wv][buf ^ 1][0][256 + (lane<<2)] = b0;
                *(float4*)&xs[wv][buf ^ 1][1][256 + (lane<<2)] = b1;
            }
        }
    }

    {
        const float4 o0 = make_float4(acc0[0], acc0[1], acc0[2], acc0[3]);
        const float4 o1 = make_float4(acc1[0], acc1[1], acc1[2], acc1[3]);
        *(float4*)(out + ((size_t)(n * CC + c0)     * HH + h) * WW + w0) = o0;
        *(float4*)(out + ((size_t)(n * CC + c0 + 1) * HH + h) * WW + w0) = o1;
    }
}

extern "C" void kernel_launch(void* const* d_in, const int* in_sizes, int n_in,
                              void* d_out, int out_size, void* d_ws, size_t ws_size,
                              hipStream_t stream) {
    const float* x  = (const float*)d_in[0];
    const float* f  = (const float*)d_in[1];
    const float* fb = (const float*)d_in[2];
    float* o = (float*)d_out;
    hipLaunchKernelGGL(dynfilter_kernel, dim3(1024), dim3(256), 0, stream,
                       x, f, fb, o);
}